// Round 2
// baseline (1032.141 us; speedup 1.0000x reference)
//
#include <hip/hip_runtime.h>
#include <hip/hip_bf16.h>

// Int8 blockwise-dequant linear: out[m,n] = sum_k x[m,k] * (qw[n,k]*scale[n*64+k/64]) + bias[n]
// M=8192 (4*2048), N=4096, K=4096.
// NOTE: harness materializes integer inputs as int32 — Wq is const int* (values -128..127),
// NOT packed int8. (Round-1 failure: read as signed char -> full-magnitude error.)
// Strategy: cast x->bf16 and dequant W->bf16 on the fly while staging into LDS, then
// 16x16x32 bf16 MFMA. 128x128 tile, BK=64 (one scale per B-tile row since k0 is 64-aligned),
// 4 waves each computing a 64x64 quadrant (4x4 MFMA tiles).

using bf16x8 = __attribute__((ext_vector_type(8))) short;  // 8 bf16 = 4 VGPRs (MFMA A/B frag)
using f32x4  = __attribute__((ext_vector_type(4))) float;  // MFMA C/D frag

constexpr int Mtot = 8192, Ntot = 4096, Ktot = 4096;
constexpr int BM = 128, BN = 128, BK = 64;
constexpr int LDSS = BK + 8;  // 72 shorts = 144 B row stride -> 36-bank offset, 2-way (free)

__device__ __forceinline__ short f2bf(float f) {
    __hip_bfloat16 h = __float2bfloat16(f);
    return *reinterpret_cast<short*>(&h);
}

__global__ __launch_bounds__(256, 2)
void int8linear_kernel(const float* __restrict__ X, const int* __restrict__ Wq,
                       const float* __restrict__ scales, const float* __restrict__ bias,
                       float* __restrict__ Out)
{
    __shared__ __align__(16) short As[BM * LDSS];
    __shared__ __align__(16) short Bs[BN * LDSS];

    const int tid = threadIdx.x;
    const int bm0 = blockIdx.y * BM;
    const int bn0 = blockIdx.x * BN;
    const int wave = tid >> 6, lane = tid & 63;
    const int wm = (wave & 1) * 64, wn = (wave >> 1) * 64;
    const int lrow = lane & 15, lquad = lane >> 4;

    // A staging: thread t covers rows {t>>4 + 16*rr, rr=0..7}, k-chunk (t&15)*4 (float4)
    const int a_kgrp = tid & 15;
    const int a_row0 = tid >> 4;
    // B staging: thread t covers row t>>1 (n), elements [(t&1)*32, +32) of the 64-elem k-slab
    const int b_row  = tid >> 1;
    const int b_koff = (tid & 1) * 32;

    f32x4 acc[4][4] = {};

    const float* xbase = X + (size_t)bm0 * Ktot;
    const int*   wbase = Wq + (size_t)(bn0 + b_row) * Ktot + b_koff;
    const float* sbase = scales + (size_t)(bn0 + b_row) * (Ktot / 64);

    for (int k0 = 0; k0 < Ktot; k0 += BK) {
        // ---- stage A: fp32 -> bf16 ----
        #pragma unroll
        for (int rr = 0; rr < 8; rr++) {
            const int row = a_row0 + rr * 16;
            const float4 v = *reinterpret_cast<const float4*>(
                xbase + (size_t)row * Ktot + k0 + a_kgrp * 4);
            short4 h;
            h.x = f2bf(v.x); h.y = f2bf(v.y); h.z = f2bf(v.z); h.w = f2bf(v.w);
            *reinterpret_cast<short4*>(&As[row * LDSS + a_kgrp * 4]) = h;
        }
        // ---- stage B: int32 weights -> dequant bf16 (one scale per row per k-tile) ----
        {
            const float s = sbase[k0 >> 6];
            int4 r[8];
            #pragma unroll
            for (int u = 0; u < 8; u++)
                r[u] = *reinterpret_cast<const int4*>(wbase + k0 + u * 4);
            short* dst = &Bs[b_row * LDSS + b_koff];
            #pragma unroll
            for (int u = 0; u < 8; u++) {
                short4 h;
                h.x = f2bf((float)r[u].x * s);
                h.y = f2bf((float)r[u].y * s);
                h.z = f2bf((float)r[u].z * s);
                h.w = f2bf((float)r[u].w * s);
                *reinterpret_cast<short4*>(dst + u * 4) = h;
            }
        }
        __syncthreads();

        // ---- compute: 2 k-steps of 16 MFMA each ----
        #pragma unroll
        for (int ks = 0; ks < 2; ks++) {
            bf16x8 af[4], bfr[4];
            #pragma unroll
            for (int i = 0; i < 4; i++)
                af[i] = *reinterpret_cast<const bf16x8*>(
                    &As[(wm + i * 16 + lrow) * LDSS + ks * 32 + lquad * 8]);
            #pragma unroll
            for (int j = 0; j < 4; j++)
                bfr[j] = *reinterpret_cast<const bf16x8*>(
                    &Bs[(wn + j * 16 + lrow) * LDSS + ks * 32 + lquad * 8]);
            #pragma unroll
            for (int i = 0; i < 4; i++)
                #pragma unroll
                for (int j = 0; j < 4; j++)
                    acc[i][j] = __builtin_amdgcn_mfma_f32_16x16x32_bf16(
                        af[i], bfr[j], acc[i][j], 0, 0, 0);
        }
        __syncthreads();
    }

    // ---- epilogue: C/D layout col=lane&15, row=(lane>>4)*4+reg ----
    #pragma unroll
    for (int j = 0; j < 4; j++) {
        const int col = bn0 + wn + j * 16 + lrow;
        const float bv = bias[col];
        #pragma unroll
        for (int i = 0; i < 4; i++) {
            const int rowb = bm0 + wm + i * 16 + lquad * 4;
            #pragma unroll
            for (int r = 0; r < 4; r++)
                Out[(size_t)(rowb + r) * Ntot + col] = acc[i][j][r] + bv;
        }
    }
}

extern "C" void kernel_launch(void* const* d_in, const int* in_sizes, int n_in,
                              void* d_out, int out_size, void* d_ws, size_t ws_size,
                              hipStream_t stream) {
    const float* X      = (const float*)d_in[0];
    const int*   Wq     = (const int*)d_in[1];
    const float* scales = (const float*)d_in[2];
    const float* bias   = (const float*)d_in[3];
    float*       Out    = (float*)d_out;

    dim3 grid(Ntot / BN, Mtot / BM);  // 32 x 64 = 2048 blocks
    int8linear_kernel<<<grid, 256, 0, stream>>>(X, Wq, scales, bias, Out);
}

// Round 3
// 555.079 us; speedup vs baseline: 1.8594x; 1.8594x over previous
//
#include <hip/hip_runtime.h>
#include <hip/hip_bf16.h>

// Int8 blockwise-dequant linear: out[m,n] = sum_k x[m,k]*(qw[n,k]*scale[n*64+k/64]) + bias[n]
// M=8192, N=4096, K=4096. Harness materializes int inputs as int32 (Wq is const int*).
//
// R3 strategy: pre-convert X->bf16 and dequant W->bf16 into d_ws (memory-bound, ~55us),
// then m97-structure bf16 GEMM: global_load_lds width=16 HBM->LDS DMA, unpadded LDS
// (wave-uniform base + lane*16 scatter == row-major stride-128B tile rows), 128x128x64
// tiles, 4 waves x (4x4 of 16x16x32 MFMA). Falls back to R2 fused kernel if ws too small.

using bf16x8 = __attribute__((ext_vector_type(8))) short;  // MFMA A/B frag (4 VGPRs)
using f32x4  = __attribute__((ext_vector_type(4))) float;  // MFMA C/D frag

constexpr int Mtot = 8192, Ntot = 4096, Ktot = 4096;
constexpr int BM = 128, BN = 128, BK = 64;

__device__ __forceinline__ short f2bf(float f) {
    __hip_bfloat16 h = __float2bfloat16(f);
    return *reinterpret_cast<short*>(&h);
}

#define GLD_LDS16(gp, lp)                                             \
    __builtin_amdgcn_global_load_lds(                                 \
        (const __attribute__((address_space(1))) void*)(gp),          \
        (__attribute__((address_space(3))) void*)(lp), 16, 0, 0)

// ---------------- pre-passes ----------------
__global__ __launch_bounds__(256)
void x_to_bf16(const float* __restrict__ X, short* __restrict__ Xb, int n) {
    const int i = (blockIdx.x * 256 + threadIdx.x) * 8;
    if (i >= n) return;
    const float4 a = *reinterpret_cast<const float4*>(X + i);
    const float4 b = *reinterpret_cast<const float4*>(X + i + 4);
    bf16x8 h;
    h[0] = f2bf(a.x); h[1] = f2bf(a.y); h[2] = f2bf(a.z); h[3] = f2bf(a.w);
    h[4] = f2bf(b.x); h[5] = f2bf(b.y); h[6] = f2bf(b.z); h[7] = f2bf(b.w);
    *reinterpret_cast<bf16x8*>(Xb + i) = h;
}

__global__ __launch_bounds__(256)
void w_to_bf16(const int* __restrict__ Wq, const float* __restrict__ scales,
               short* __restrict__ Wb, int n) {
    const int i = (blockIdx.x * 256 + threadIdx.x) * 8;
    if (i >= n) return;
    const float s = scales[i >> 6];  // 8 consecutive elems share one 64-block
    const int4 a = *reinterpret_cast<const int4*>(Wq + i);
    const int4 b = *reinterpret_cast<const int4*>(Wq + i + 4);
    bf16x8 h;
    h[0] = f2bf((float)a.x * s); h[1] = f2bf((float)a.y * s);
    h[2] = f2bf((float)a.z * s); h[3] = f2bf((float)a.w * s);
    h[4] = f2bf((float)b.x * s); h[5] = f2bf((float)b.y * s);
    h[6] = f2bf((float)b.z * s); h[7] = f2bf((float)b.w * s);
    *reinterpret_cast<bf16x8*>(Wb + i) = h;
}

// ---------------- m97-structure bf16 GEMM (A[M,K] x B[N,K]^T) ----------------
__global__ __launch_bounds__(256, 2)
void gemm_bf16_bt(const short* __restrict__ A, const short* __restrict__ B,
                  const float* __restrict__ bias, float* __restrict__ Out)
{
    __shared__ __align__(16) short As[BM * BK];  // 16 KB, unpadded (DMA layout)
    __shared__ __align__(16) short Bs[BN * BK];  // 16 KB

    const int tid = threadIdx.x;
    const int bm0 = blockIdx.y * BM, bn0 = blockIdx.x * BN;
    const int wave = tid >> 6, lane = tid & 63;
    const int wm = (wave & 1) * 64, wn = (wave >> 1) * 64;
    const int lrow = lane & 15, lquad = lane >> 4;

    // DMA staging: wave issues 4 loads per operand per k-iter; each load:
    // lane l -> global row slab+ (l>>3), k-bytes (l&7)*16; LDS = base + l*16
    const int srow = lane >> 3;       // row within 8-row slab
    const int skk  = (lane & 7) * 8;  // k element offset

    f32x4 acc[4][4] = {};

    const short* Ab = A + (size_t)(bm0 + wave * 32 + srow) * Ktot + skk;
    const short* Bb = B + (size_t)(bn0 + wave * 32 + srow) * Ktot + skk;
    short* AsW = &As[(wave * 32) * BK];
    short* BsW = &Bs[(wave * 32) * BK];

    for (int k0 = 0; k0 < Ktot; k0 += BK) {
        #pragma unroll
        for (int q = 0; q < 4; q++) {
            GLD_LDS16(Ab + (size_t)(q * 8) * Ktot + k0, AsW + (q * 8) * BK);
            GLD_LDS16(Bb + (size_t)(q * 8) * Ktot + k0, BsW + (q * 8) * BK);
        }
        __syncthreads();  // drains vmcnt(0): DMA complete

        #pragma unroll
        for (int ks = 0; ks < 2; ks++) {
            bf16x8 af[4], bfr[4];
            #pragma unroll
            for (int i = 0; i < 4; i++)
                af[i] = *reinterpret_cast<const bf16x8*>(
                    &As[(wm + i * 16 + lrow) * BK + ks * 32 + lquad * 8]);
            #pragma unroll
            for (int j = 0; j < 4; j++)
                bfr[j] = *reinterpret_cast<const bf16x8*>(
                    &Bs[(wn + j * 16 + lrow) * BK + ks * 32 + lquad * 8]);
            #pragma unroll
            for (int i = 0; i < 4; i++)
                #pragma unroll
                for (int j = 0; j < 4; j++)
                    acc[i][j] = __builtin_amdgcn_mfma_f32_16x16x32_bf16(
                        af[i], bfr[j], acc[i][j], 0, 0, 0);
        }
        __syncthreads();
    }

    // epilogue: C/D layout col=lane&15, row=(lane>>4)*4+reg
    #pragma unroll
    for (int j = 0; j < 4; j++) {
        const int col = bn0 + wn + j * 16 + lrow;
        const float bv = bias[col];
        #pragma unroll
        for (int i = 0; i < 4; i++) {
            const int rowb = bm0 + wm + i * 16 + lquad * 4;
            #pragma unroll
            for (int r = 0; r < 4; r++)
                Out[(size_t)(rowb + r) * Ntot + col] = acc[i][j][r] + bv;
        }
    }
}

// ---------------- R2 fused fallback (ws too small) ----------------
constexpr int LDSS = BK + 8;
__global__ __launch_bounds__(256, 2)
void int8linear_fused(const float* __restrict__ X, const int* __restrict__ Wq,
                      const float* __restrict__ scales, const float* __restrict__ bias,
                      float* __restrict__ Out)
{
    __shared__ __align__(16) short As[BM * LDSS];
    __shared__ __align__(16) short Bs[BN * LDSS];
    const int tid = threadIdx.x;
    const int bm0 = blockIdx.y * BM, bn0 = blockIdx.x * BN;
    const int wave = tid >> 6, lane = tid & 63;
    const int wm = (wave & 1) * 64, wn = (wave >> 1) * 64;
    const int lrow = lane & 15, lquad = lane >> 4;
    const int a_kgrp = tid & 15, a_row0 = tid >> 4;
    const int b_row = tid >> 1, b_koff = (tid & 1) * 32;
    f32x4 acc[4][4] = {};
    const float* xbase = X + (size_t)bm0 * Ktot;
    const int*   wbase = Wq + (size_t)(bn0 + b_row) * Ktot + b_koff;
    const float* sbase = scales + (size_t)(bn0 + b_row) * (Ktot / 64);
    for (int k0 = 0; k0 < Ktot; k0 += BK) {
        #pragma unroll
        for (int rr = 0; rr < 8; rr++) {
            const int row = a_row0 + rr * 16;
            const float4 v = *reinterpret_cast<const float4*>(
                xbase + (size_t)row * Ktot + k0 + a_kgrp * 4);
            short4 h; h.x = f2bf(v.x); h.y = f2bf(v.y); h.z = f2bf(v.z); h.w = f2bf(v.w);
            *reinterpret_cast<short4*>(&As[row * LDSS + a_kgrp * 4]) = h;
        }
        {
            const float s = sbase[k0 >> 6];
            int4 r[8];
            #pragma unroll
            for (int u = 0; u < 8; u++) r[u] = *reinterpret_cast<const int4*>(wbase + k0 + u * 4);
            short* dst = &Bs[b_row * LDSS + b_koff];
            #pragma unroll
            for (int u = 0; u < 8; u++) {
                short4 h;
                h.x = f2bf((float)r[u].x * s); h.y = f2bf((float)r[u].y * s);
                h.z = f2bf((float)r[u].z * s); h.w = f2bf((float)r[u].w * s);
                *reinterpret_cast<short4*>(dst + u * 4) = h;
            }
        }
        __syncthreads();
        #pragma unroll
        for (int ks = 0; ks < 2; ks++) {
            bf16x8 af[4], bfr[4];
            #pragma unroll
            for (int i = 0; i < 4; i++)
                af[i] = *reinterpret_cast<const bf16x8*>(&As[(wm + i*16 + lrow) * LDSS + ks*32 + lquad*8]);
            #pragma unroll
            for (int j = 0; j < 4; j++)
                bfr[j] = *reinterpret_cast<const bf16x8*>(&Bs[(wn + j*16 + lrow) * LDSS + ks*32 + lquad*8]);
            #pragma unroll
            for (int i = 0; i < 4; i++)
                #pragma unroll
                for (int j = 0; j < 4; j++)
                    acc[i][j] = __builtin_amdgcn_mfma_f32_16x16x32_bf16(af[i], bfr[j], acc[i][j], 0, 0, 0);
        }
        __syncthreads();
    }
    #pragma unroll
    for (int j = 0; j < 4; j++) {
        const int col = bn0 + wn + j * 16 + lrow;
        const float bv = bias[col];
        #pragma unroll
        for (int i = 0; i < 4; i++) {
            const int rowb = bm0 + wm + i * 16 + lquad * 4;
            #pragma unroll
            for (int r = 0; r < 4; r++)
                Out[(size_t)(rowb + r) * Ntot + col] = acc[i][j][r] + bv;
        }
    }
}

extern "C" void kernel_launch(void* const* d_in, const int* in_sizes, int n_in,
                              void* d_out, int out_size, void* d_ws, size_t ws_size,
                              hipStream_t stream) {
    const float* X      = (const float*)d_in[0];
    const int*   Wq     = (const int*)d_in[1];
    const float* scales = (const float*)d_in[2];
    const float* bias   = (const float*)d_in[3];
    float*       Out    = (float*)d_out;

    const size_t xN = (size_t)Mtot * Ktot;          // 33,554,432
    const size_t wN = (size_t)Ntot * Ktot;          // 16,777,216
    const size_t need = xN * 2 + wN * 2;            // ~100.7 MB

    dim3 grid(Ntot / BN, Mtot / BM);  // 32 x 64 = 2048 blocks

    if (ws_size >= need) {
        short* Xb = (short*)d_ws;
        short* Wb = Xb + xN;
        x_to_bf16<<<(int)(xN / 8 / 256), 256, 0, stream>>>(X, Xb, (int)xN);
        w_to_bf16<<<(int)(wN / 8 / 256), 256, 0, stream>>>(Wq, scales, Wb, (int)wN);
        gemm_bf16_bt<<<grid, 256, 0, stream>>>(Xb, Wb, bias, Out);
    } else {
        int8linear_fused<<<grid, 256, 0, stream>>>(X, Wq, scales, bias, Out);
    }
}